// Round 3
// baseline (477.766 us; speedup 1.0000x reference)
//
#include <hip/hip_runtime.h>
#include <hip/hip_bf16.h>
#include <hip/hip_fp16.h>

typedef _Float16 f16;
typedef f16 f16x8 __attribute__((ext_vector_type(8)));
typedef float f32x4 __attribute__((ext_vector_type(4)));

#define NTOK 32768   // B*S = 8*4096 tokens
#define KDIM 512
#define SLEN 4096
#define BATCH 8

__device__ __forceinline__ float fast_tanh(float x) {
    float ax = fabsf(x);
    float t = __expf(-2.0f * ax);
    float r = (1.0f - t) / (1.0f + t);
    return copysignf(r, x);
}

// C[n, j] = act( sum_k A[n,k] * W[j,k] (+ sum_k A2[n,k] * W2[j,k]) + bias )
// A: [NTOK, 512] (fp32 input if A_F32 else fp16 intermediate). W: [512,512] fp32.
// OUT_MODE 0: fp16 to ws buffer [NTOK,512]. OUT_MODE 1: fp32 to d_out, [S,B,H] layout.
template<bool A_F32, bool DUAL, bool TANH, int OUT_MODE>
__global__ __launch_bounds__(256)
void gemm_kernel(const void* __restrict__ Ap, const void* __restrict__ A2p,
                 const float* __restrict__ W1, const float* __restrict__ W2,
                 const float* __restrict__ b1, const float* __restrict__ b2,
                 void* __restrict__ Cp)
{
    __shared__ f16 A_s[128][64];
    __shared__ f16 B_s[128][64];

    const int tid = threadIdx.x;
    const int n0 = blockIdx.y * 128;   // token-row tile
    const int j0 = blockIdx.x * 128;   // output-col tile

    const int lane = tid & 63;
    const int wave = tid >> 6;
    const int wm = wave >> 1, wn = wave & 1;      // 2x2 waves -> 64x64 each
    const int fr = lane & 15;                     // fragment row (m or n)
    const int fk = (lane >> 4) * 8;               // fragment k offset (quad*8)

    f32x4 acc[4][4] = {};

    const int KT = DUAL ? 16 : 8;
    for (int kt = 0; kt < KT; ++kt) {
        const bool second = DUAL && (kt >= 8);
        const int k0 = (second ? (kt - 8) : kt) * 64;
        const float* __restrict__ W = second ? W2 : W1;

        // ---- stage A_s and B_s: 128 rows x 64 k, 16B chunks ----
        #pragma unroll
        for (int p = 0; p < 4; ++p) {
            const int id  = p * 256 + tid;
            const int row = id >> 3;        // 0..127
            const int kc  = (id & 7) * 8;   // 0,8,..,56

            // A tile
            if (A_F32 && !second) {
                const float* A32 = (const float*)Ap;
                const float4 v0 = *(const float4*)&A32[(size_t)(n0 + row) * KDIM + k0 + kc];
                const float4 v1 = *(const float4*)&A32[(size_t)(n0 + row) * KDIM + k0 + kc + 4];
                f16x8 h;
                h[0] = (f16)v0.x; h[1] = (f16)v0.y; h[2] = (f16)v0.z; h[3] = (f16)v0.w;
                h[4] = (f16)v1.x; h[5] = (f16)v1.y; h[6] = (f16)v1.z; h[7] = (f16)v1.w;
                *(f16x8*)&A_s[row][kc] = h;
            } else {
                const f16* A16 = (const f16*)(second ? A2p : Ap);
                *(f16x8*)&A_s[row][kc] = *(const f16x8*)&A16[(size_t)(n0 + row) * KDIM + k0 + kc];
            }
            // B tile (weights are fp32 in HBM; convert to fp16 — values ~0.044, exact-ish)
            {
                const float4 v0 = *(const float4*)&W[(size_t)(j0 + row) * KDIM + k0 + kc];
                const float4 v1 = *(const float4*)&W[(size_t)(j0 + row) * KDIM + k0 + kc + 4];
                f16x8 h;
                h[0] = (f16)v0.x; h[1] = (f16)v0.y; h[2] = (f16)v0.z; h[3] = (f16)v0.w;
                h[4] = (f16)v1.x; h[5] = (f16)v1.y; h[6] = (f16)v1.z; h[7] = (f16)v1.w;
                *(f16x8*)&B_s[row][kc] = h;
            }
        }
        __syncthreads();

        // ---- MFMA: 2 k-steps of 32, 4x4 tiles of 16x16 per wave ----
        #pragma unroll
        for (int kk = 0; kk < 64; kk += 32) {
            f16x8 a[4], b[4];
            #pragma unroll
            for (int t = 0; t < 4; ++t)
                a[t] = *(const f16x8*)&A_s[wm * 64 + t * 16 + fr][kk + fk];
            #pragma unroll
            for (int t = 0; t < 4; ++t)
                b[t] = *(const f16x8*)&B_s[wn * 64 + t * 16 + fr][kk + fk];
            #pragma unroll
            for (int im = 0; im < 4; ++im)
                #pragma unroll
                for (int jn = 0; jn < 4; ++jn)
                    acc[im][jn] = __builtin_amdgcn_mfma_f32_16x16x32_f16(
                        a[im], b[jn], acc[im][jn], 0, 0, 0);
        }
        __syncthreads();
    }

    // ---- epilogue: D mapping col = lane&15, row = (lane>>4)*4 + r ----
    const int r0 = (lane >> 4) * 4;
    const int c  = lane & 15;
    #pragma unroll
    for (int jn = 0; jn < 4; ++jn) {
        const int j = j0 + wn * 64 + jn * 16 + c;
        float bias = b1[j];
        if (TANH) bias += b2[j];
        #pragma unroll
        for (int im = 0; im < 4; ++im) {
            #pragma unroll
            for (int r = 0; r < 4; ++r) {
                const int n = n0 + wm * 64 + im * 16 + r0 + r;
                float v = acc[im][jn][r] + bias;
                if (TANH) v = fast_tanh(v);
                if (OUT_MODE == 0) {
                    ((f16*)Cp)[(size_t)n * KDIM + j] = (f16)v;
                } else {
                    // outputs[s, b, j] with n = b*SLEN + s ; fp32 out
                    const int s = n & (SLEN - 1);
                    const int bb = n >> 12;
                    ((float*)Cp)[(size_t)(s * BATCH + bb) * KDIM + j] = v;
                }
            }
        }
    }
}

// hs_final: h2 rows at n = b*S + (S-1), fp16 -> fp32, appended after outputs
__global__ void hs_kernel(const f16* __restrict__ h2, float* __restrict__ out)
{
    const int t = blockIdx.x * 256 + threadIdx.x;   // 0..4095
    const int b = t >> 9;
    const int j = t & 511;
    out[t] = (float)h2[((size_t)b * SLEN + (SLEN - 1)) * KDIM + j];
}

extern "C" void kernel_launch(void* const* d_in, const int* in_sizes, int n_in,
                              void* d_out, int out_size, void* d_ws, size_t ws_size,
                              hipStream_t stream)
{
    (void)in_sizes; (void)n_in; (void)out_size; (void)ws_size;

    const float* xs     = (const float*)d_in[0];
    const float* W_xh0  = (const float*)d_in[1];
    const float* b_xh0  = (const float*)d_in[2];
    /* d_in[3] = W_hh0: unused (hs == 0, only its bias matters) */
    const float* b_hh0  = (const float*)d_in[4];
    const float* W_hy0  = (const float*)d_in[5];
    const float* b_hy0  = (const float*)d_in[6];
    const float* W_xh_h = (const float*)d_in[7];
    const float* b_xh_h = (const float*)d_in[8];
    const float* W_hh_h = (const float*)d_in[9];
    const float* b_hh_h = (const float*)d_in[10];
    const float* W_hy_h = (const float*)d_in[11];
    const float* b_hy_h = (const float*)d_in[12];

    f16* buf0 = (f16*)d_ws;                           // 32 MB each
    f16* buf1 = buf0 + (size_t)NTOK * KDIM;
    f16* buf2 = buf1 + (size_t)NTOK * KDIM;

    const size_t WOFF = (size_t)KDIM * KDIM;          // 262144
    dim3 grid(4, 256), block(256);

    // K1: h0 = tanh(X @ W_xh0^T + b_xh0 + b_hh0) -> buf0
    gemm_kernel<true, false, true, 0><<<grid, block, 0, stream>>>(
        xs, nullptr, W_xh0, nullptr, b_xh0, b_hh0, buf0);
    // K2: y0 = h0 @ W_hy0^T + b_hy0 -> buf1
    gemm_kernel<false, false, false, 0><<<grid, block, 0, stream>>>(
        buf0, nullptr, W_hy0, nullptr, b_hy0, nullptr, buf1);
    // K3: h1 = tanh(h0 @ W_hh_h[0]^T + y0 @ W_xh_h[0]^T + b_hh_h[0] + b_xh_h[0]) -> buf2
    gemm_kernel<false, true, true, 0><<<grid, block, 0, stream>>>(
        buf0, buf1, W_hh_h, W_xh_h, b_hh_h, b_xh_h, buf2);
    // K4: y1 = h1 @ W_hy_h[0]^T + b_hy_h[0] -> buf0
    gemm_kernel<false, false, false, 0><<<grid, block, 0, stream>>>(
        buf2, nullptr, W_hy_h, nullptr, b_hy_h, nullptr, buf0);
    // K5: h2 = tanh(h1 @ W_hh_h[1]^T + y1 @ W_xh_h[1]^T + b_hh_h[1] + b_xh_h[1]) -> buf1
    gemm_kernel<false, true, true, 0><<<grid, block, 0, stream>>>(
        buf2, buf0, W_hh_h + WOFF, W_xh_h + WOFF, b_hh_h + KDIM, b_xh_h + KDIM, buf1);
    // K6: y2 = h2 @ W_hy_h[1]^T + b_hy_h[1] -> d_out (fp32, [S,B,H] layout)
    gemm_kernel<false, false, false, 1><<<grid, block, 0, stream>>>(
        buf1, nullptr, W_hy_h + WOFF, nullptr, b_hy_h + KDIM, nullptr, d_out);
    // hs_final: h2[:, S-1, :] -> tail of d_out (fp32)
    hs_kernel<<<16, 256, 0, stream>>>(
        buf1, (float*)d_out + (size_t)SLEN * BATCH * KDIM);
}

// Round 4
// 419.297 us; speedup vs baseline: 1.1394x; 1.1394x over previous
//
#include <hip/hip_runtime.h>
#include <hip/hip_fp16.h>

typedef _Float16 f16;
typedef f16 f16x8 __attribute__((ext_vector_type(8)));
typedef float f32x4 __attribute__((ext_vector_type(4)));

#define NTOK 32768   // B*S
#define KDIM 512
#define SLEN 4096
#define BATCH 8

#define GLOAD_LDS16(g, l) __builtin_amdgcn_global_load_lds(                 \
    (const __attribute__((address_space(1))) void*)(g),                     \
    (__attribute__((address_space(3))) void*)(l), 16, 0, 0)

__device__ __forceinline__ float fast_tanh(float x) {
    float ax = fabsf(x);
    float t = __expf(-2.0f * ax);
    float r = (1.0f - t) / (1.0f + t);
    return copysignf(r, x);
}

// C[n,j] = act( sum_k A[n,k]*W[j,k] (+ sum_k A2[n,k]*W2[j,k]) + bias )
// A: f16 [NTOK,512]. W: fp32 [512,512] (cvt->f16 in staging).
// LDS layout XOR-swizzled in 16B chunks: LDS[r][c] = G[r][c ^ (r&7)].
// OUT_MODE 0: f16 -> ws [NTOK,512]. OUT_MODE 1: fp32 -> d_out [S,B,H].
template<bool DUAL, bool TANH, int OUT_MODE>
__global__ __launch_bounds__(256)
void gemm_kernel(const f16* __restrict__ A1, const f16* __restrict__ A2,
                 const float* __restrict__ W1, const float* __restrict__ W2,
                 const float* __restrict__ b1, const float* __restrict__ b2,
                 void* __restrict__ Cp)
{
    __shared__ f16 A_s[128][64];
    __shared__ f16 B_s[128][64];

    const int tid  = threadIdx.x;
    const int bid  = blockIdx.x;
    // XCD-aware map: xcd = bid&7 owns n-tiles [32*xcd, 32*xcd+32), all 4 j-tiles.
    const int xcd  = bid & 7;
    const int idx  = bid >> 3;
    const int j0   = (idx & 3) * 128;
    const int n0   = ((xcd << 5) | (idx >> 2)) * 128;

    const int lane = tid & 63;
    const int wave = tid >> 6;
    const int wm = wave >> 1, wn = wave & 1;   // 2x2 waves, 64x64 each
    const int fr = lane & 15;
    const int q  = lane >> 4;
    const int sw = fr & 7;                     // read-side swizzle

    // A-staging (DMA): lane covers row base+ (lane>>3), global chunk (lane&7)^(lane>>3)
    const int ar8 = lane >> 3;
    const int ach = (lane & 7) ^ ar8;

    f32x4 acc[4][4] = {};

    const int KT = DUAL ? 16 : 8;
    for (int kt = 0; kt < KT; ++kt) {
        const bool second = DUAL && (kt >= 8);
        const int k0 = (second ? (kt - 8) : kt) * 64;
        const f16*   __restrict__ A = second ? A2 : A1;
        const float* __restrict__ W = second ? W2 : W1;

        // ---- A tile: 4 global_load_lds_dwordx4 per wave, swizzled source ----
        #pragma unroll
        for (int p = 0; p < 4; ++p) {
            const int r8 = wave * 32 + p * 8;               // wave-uniform row base
            const f16* gA = &A[(size_t)(n0 + r8 + ar8) * KDIM + k0 + (ach << 3)];
            GLOAD_LDS16(gA, &A_s[r8][0]);
        }
        // ---- B tile: fp32 load + cvt, swizzled LDS write ----
        #pragma unroll
        for (int p = 0; p < 4; ++p) {
            const int id  = p * 256 + tid;
            const int row = id >> 3;          // 0..127
            const int c   = id & 7;           // global chunk
            const float4 v0 = *(const float4*)&W[(size_t)(j0 + row) * KDIM + k0 + c * 8];
            const float4 v1 = *(const float4*)&W[(size_t)(j0 + row) * KDIM + k0 + c * 8 + 4];
            f16x8 h;
            h[0] = (f16)v0.x; h[1] = (f16)v0.y; h[2] = (f16)v0.z; h[3] = (f16)v0.w;
            h[4] = (f16)v1.x; h[5] = (f16)v1.y; h[6] = (f16)v1.z; h[7] = (f16)v1.w;
            *(f16x8*)&B_s[row][(c ^ (row & 7)) << 3] = h;
        }
        __syncthreads();

        // ---- MFMA: 2 k-steps of 32 ----
        #pragma unroll
        for (int kc = 0; kc < 8; kc += 4) {   // chunk base per k-step
            f16x8 a[4], b[4];
            #pragma unroll
            for (int t = 0; t < 4; ++t)
                a[t] = *(const f16x8*)&A_s[wm * 64 + t * 16 + fr][((kc + q) ^ sw) << 3];
            #pragma unroll
            for (int t = 0; t < 4; ++t)
                b[t] = *(const f16x8*)&B_s[wn * 64 + t * 16 + fr][((kc + q) ^ sw) << 3];
            #pragma unroll
            for (int im = 0; im < 4; ++im)
                #pragma unroll
                for (int jn = 0; jn < 4; ++jn)
                    acc[im][jn] = __builtin_amdgcn_mfma_f32_16x16x32_f16(
                        a[im], b[jn], acc[im][jn], 0, 0, 0);
        }
        __syncthreads();
    }

    // ---- epilogue: D mapping col = lane&15, row = (lane>>4)*4 + r ----
    const int r0 = q * 4;
    const int c  = fr;
    #pragma unroll
    for (int jn = 0; jn < 4; ++jn) {
        const int j = j0 + wn * 64 + jn * 16 + c;
        float bias = b1[j];
        if (TANH) bias += b2[j];
        #pragma unroll
        for (int im = 0; im < 4; ++im) {
            #pragma unroll
            for (int r = 0; r < 4; ++r) {
                const int n = n0 + wm * 64 + im * 16 + r0 + r;
                float v = acc[im][jn][r] + bias;
                if (TANH) v = fast_tanh(v);
                if (OUT_MODE == 0) {
                    ((f16*)Cp)[(size_t)n * KDIM + j] = (f16)v;
                } else {
                    const int s  = n & (SLEN - 1);
                    const int bb = n >> 12;
                    ((float*)Cp)[(size_t)(s * BATCH + bb) * KDIM + j] = v;
                }
            }
        }
    }
}

// fp32 -> f16, 8 elements/thread
__global__ __launch_bounds__(256)
void cvt_kernel(const float* __restrict__ src, f16* __restrict__ dst)
{
    const int i = blockIdx.x * 256 + threadIdx.x;
    const float4 v0 = *(const float4*)&src[(size_t)i * 8];
    const float4 v1 = *(const float4*)&src[(size_t)i * 8 + 4];
    f16x8 h;
    h[0] = (f16)v0.x; h[1] = (f16)v0.y; h[2] = (f16)v0.z; h[3] = (f16)v0.w;
    h[4] = (f16)v1.x; h[5] = (f16)v1.y; h[6] = (f16)v1.z; h[7] = (f16)v1.w;
    *(f16x8*)&dst[(size_t)i * 8] = h;
}

// hs_final: h2 rows at n = b*S + (S-1), f16 -> fp32
__global__ void hs_kernel(const f16* __restrict__ h2, float* __restrict__ out)
{
    const int t = blockIdx.x * 256 + threadIdx.x;   // 0..4095
    const int b = t >> 9;
    const int j = t & 511;
    out[t] = (float)h2[((size_t)b * SLEN + (SLEN - 1)) * KDIM + j];
}

extern "C" void kernel_launch(void* const* d_in, const int* in_sizes, int n_in,
                              void* d_out, int out_size, void* d_ws, size_t ws_size,
                              hipStream_t stream)
{
    (void)in_sizes; (void)n_in; (void)out_size; (void)ws_size;

    const float* xs     = (const float*)d_in[0];
    const float* W_xh0  = (const float*)d_in[1];
    const float* b_xh0  = (const float*)d_in[2];
    /* d_in[3] = W_hh0: unused (hs == 0, only its bias matters) */
    const float* b_hh0  = (const float*)d_in[4];
    const float* W_hy0  = (const float*)d_in[5];
    const float* b_hy0  = (const float*)d_in[6];
    const float* W_xh_h = (const float*)d_in[7];
    const float* b_xh_h = (const float*)d_in[8];
    const float* W_hh_h = (const float*)d_in[9];
    const float* b_hh_h = (const float*)d_in[10];
    const float* W_hy_h = (const float*)d_in[11];
    const float* b_hy_h = (const float*)d_in[12];

    f16* buf0 = (f16*)d_ws;                           // 32 MB each
    f16* buf1 = buf0 + (size_t)NTOK * KDIM;
    f16* buf2 = buf1 + (size_t)NTOK * KDIM;

    const size_t WOFF = (size_t)KDIM * KDIM;          // 262144
    dim3 grid(1024), block(256);

    // P: X fp32 -> f16 into buf2 (buf2 is free until K3 overwrites it)
    cvt_kernel<<<NTOK * KDIM / (256 * 8), 256, 0, stream>>>(xs, buf2);
    // K1: h0 = tanh(X16 @ W_xh0^T + b_xh0 + b_hh0) -> buf0
    gemm_kernel<false, true, 0><<<grid, block, 0, stream>>>(
        buf2, nullptr, W_xh0, nullptr, b_xh0, b_hh0, buf0);
    // K2: y0 = h0 @ W_hy0^T + b_hy0 -> buf1
    gemm_kernel<false, false, 0><<<grid, block, 0, stream>>>(
        buf0, nullptr, W_hy0, nullptr, b_hy0, nullptr, buf1);
    // K3: h1 = tanh(h0 @ W_hh_h[0]^T + y0 @ W_xh_h[0]^T + biases) -> buf2
    gemm_kernel<true, true, 0><<<grid, block, 0, stream>>>(
        buf0, buf1, W_hh_h, W_xh_h, b_hh_h, b_xh_h, buf2);
    // K4: y1 = h1 @ W_hy_h[0]^T + b_hy_h[0] -> buf0
    gemm_kernel<false, false, 0><<<grid, block, 0, stream>>>(
        buf2, nullptr, W_hy_h, nullptr, b_hy_h, nullptr, buf0);
    // K5: h2 = tanh(h1 @ W_hh_h[1]^T + y1 @ W_xh_h[1]^T + biases) -> buf1
    gemm_kernel<true, true, 0><<<grid, block, 0, stream>>>(
        buf2, buf0, W_hh_h + WOFF, W_xh_h + WOFF, b_hh_h + KDIM, b_xh_h + KDIM, buf1);
    // K6: y2 = h2 @ W_hy_h[1]^T + b_hy_h[1] -> d_out (fp32, [S,B,H])
    gemm_kernel<false, false, 1><<<grid, block, 0, stream>>>(
        buf1, nullptr, W_hy_h + WOFF, nullptr, b_hy_h + KDIM, nullptr, d_out);
    // hs_final: h2[:, S-1, :] -> tail of d_out (fp32)
    hs_kernel<<<16, 256, 0, stream>>>(
        buf1, (float*)d_out + (size_t)SLEN * BATCH * KDIM);
}

// Round 5
// 331.678 us; speedup vs baseline: 1.4405x; 1.2642x over previous
//
#include <hip/hip_runtime.h>
#include <hip/hip_fp16.h>

typedef _Float16 f16;
typedef f16 f16x4 __attribute__((ext_vector_type(4)));
typedef f16 f16x8 __attribute__((ext_vector_type(8)));
typedef float f32x4 __attribute__((ext_vector_type(4)));

#define NTOK 32768   // B*S
#define KDIM 512
#define SLEN 4096
#define BATCH 8
#define WSZ  262144  // 512*512

#define GLOAD_LDS16(g, l) __builtin_amdgcn_global_load_lds(                 \
    (const __attribute__((address_space(1))) void*)(g),                     \
    (__attribute__((address_space(3))) void*)(l), 16, 0, 0)

__device__ __forceinline__ float fast_tanh(float x) {
    float ax = fabsf(x);
    float t = __expf(-2.0f * ax);
    float r = (1.0f - t) / (1.0f + t);
    return copysignf(r, x);
}

// C[n,j] = post( sum_k A[n,k]*W[j,k] + bias (+ Cadd[n,j]) )
// A,W f16 row-major [*,512]; LDS XOR-swizzled (16B chunks), both staged via DMA.
// OUT_MODE 0: f16 [n*512+j]. OUT_MODE 1: fp32 d_out [S,B,H] with n = b*SLEN+s.
template<bool BIAS1, bool BIAS2, bool ADDC, bool TANH, int OUT_MODE, bool SMALL>
__global__ __launch_bounds__(256)
void gemm16(const f16* __restrict__ A, const f16* __restrict__ W,
            const float* __restrict__ b1, const float* __restrict__ b2,
            const float* __restrict__ Cadd, void* __restrict__ Cp)
{
    __shared__ f16 A_s[128][64];
    __shared__ f16 B_s[128][64];

    const int tid = threadIdx.x;
    const int bid = blockIdx.x;
    int n0, j0;
    if (SMALL) {                      // 16-block fold GEMM (512x512)
        n0 = (bid >> 2) * 128;
        j0 = (bid & 3) * 128;
    } else {                          // XCD-aware: xcd owns 32 n-tiles x 4 j-tiles
        const int xcd = bid & 7, idx = bid >> 3;
        j0 = (idx & 3) * 128;
        n0 = ((xcd << 5) | (idx >> 2)) * 128;
    }

    const int lane = tid & 63, wave = tid >> 6;
    const int wm = wave >> 1, wn = wave & 1;    // 2x2 waves, 64x64 each
    const int fr = lane & 15, q = lane >> 4, sw = fr & 7;
    const int ar8 = lane >> 3;                  // DMA: row within 8-row group
    const int ach = (lane & 7) ^ ar8;           // DMA: swizzled source chunk

    f32x4 acc[4][4] = {};

    for (int kt = 0; kt < 8; ++kt) {
        const int k0 = kt * 64;
        #pragma unroll
        for (int p = 0; p < 4; ++p) {
            const int r8 = wave * 32 + p * 8;   // wave-uniform row base
            GLOAD_LDS16(&A[(size_t)(n0 + r8 + ar8) * KDIM + k0 + (ach << 3)], &A_s[r8][0]);
            GLOAD_LDS16(&W[(size_t)(j0 + r8 + ar8) * KDIM + k0 + (ach << 3)], &B_s[r8][0]);
        }
        __syncthreads();

        #pragma unroll
        for (int kc = 0; kc < 8; kc += 4) {
            f16x8 a[4], b[4];
            #pragma unroll
            for (int t = 0; t < 4; ++t)
                a[t] = *(const f16x8*)&A_s[wm * 64 + t * 16 + fr][((kc + q) ^ sw) << 3];
            #pragma unroll
            for (int t = 0; t < 4; ++t)
                b[t] = *(const f16x8*)&B_s[wn * 64 + t * 16 + fr][((kc + q) ^ sw) << 3];
            #pragma unroll
            for (int im = 0; im < 4; ++im)
                #pragma unroll
                for (int jn = 0; jn < 4; ++jn)
                    acc[im][jn] = __builtin_amdgcn_mfma_f32_16x16x32_f16(
                        a[im], b[jn], acc[im][jn], 0, 0, 0);
        }
        __syncthreads();
    }

    const int r0 = q * 4, c = fr;
    #pragma unroll
    for (int jn = 0; jn < 4; ++jn) {
        const int j = j0 + wn * 64 + jn * 16 + c;
        float base = 0.f;
        if (BIAS1) base += b1[j];
        if (BIAS2) base += b2[j];
        #pragma unroll
        for (int im = 0; im < 4; ++im) {
            #pragma unroll
            for (int r = 0; r < 4; ++r) {
                const int n = n0 + wm * 64 + im * 16 + r0 + r;
                float v = acc[im][jn][r] + base;
                if (ADDC) v += Cadd[(size_t)n * KDIM + j];
                if (TANH) v = fast_tanh(v);
                if (OUT_MODE == 0) {
                    ((f16*)Cp)[(size_t)n * KDIM + j] = (f16)v;
                } else {
                    const int s = n & (SLEN - 1), bb = n >> 12;
                    ((float*)Cp)[(size_t)(s * BATCH + bb) * KDIM + j] = v;
                }
            }
        }
    }
}

// fp32 -> f16, 8 elements/thread
__global__ __launch_bounds__(256)
void cvt_kernel(const float* __restrict__ src, f16* __restrict__ dst)
{
    const int i = blockIdx.x * 256 + threadIdx.x;
    const float4 v0 = *(const float4*)&src[(size_t)i * 8];
    const float4 v1 = *(const float4*)&src[(size_t)i * 8 + 4];
    f16x8 h;
    h[0] = (f16)v0.x; h[1] = (f16)v0.y; h[2] = (f16)v0.z; h[3] = (f16)v0.w;
    h[4] = (f16)v1.x; h[5] = (f16)v1.y; h[6] = (f16)v1.z; h[7] = (f16)v1.w;
    *(f16x8*)&dst[(size_t)i * 8] = h;
}

// 512x512: out[c][r] = (f16) in[r][c]
__global__ __launch_bounds__(256)
void tcvt_kernel(const float* __restrict__ in, f16* __restrict__ out)
{
    __shared__ float t[64][65];
    const int c0 = (blockIdx.x & 7) * 64, r0 = (blockIdx.x >> 3) * 64;
    const int tr = threadIdx.x >> 4;           // 0..15
    const int tc = (threadIdx.x & 15) * 4;     // 0..60
    #pragma unroll
    for (int i = 0; i < 4; ++i) {
        const float4 v = *(const float4*)&in[(size_t)(r0 + tr + 16 * i) * 512 + c0 + tc];
        t[tr + 16 * i][tc + 0] = v.x; t[tr + 16 * i][tc + 1] = v.y;
        t[tr + 16 * i][tc + 2] = v.z; t[tr + 16 * i][tc + 3] = v.w;
    }
    __syncthreads();
    #pragma unroll
    for (int i = 0; i < 4; ++i) {
        const int cl = tr + 16 * i;            // out row (= in col)
        f16x4 h;
        h[0] = (f16)t[tc + 0][cl]; h[1] = (f16)t[tc + 1][cl];
        h[2] = (f16)t[tc + 2][cl]; h[3] = (f16)t[tc + 3][cl];
        *(f16x4*)&out[(size_t)(c0 + cl) * 512 + r0 + tc] = h;
    }
}

// b_eff[j] = b_hh[j] + b_xh[j] + sum_k W_xh[j,k] * b_hy[k]   (all fp32)
__global__ __launch_bounds__(256)
void beff_kernel(const float* __restrict__ W_xh, const float* __restrict__ b_hy,
                 const float* __restrict__ b_hh, const float* __restrict__ b_xh,
                 float* __restrict__ out)
{
    const int j = blockIdx.x * 256 + threadIdx.x;
    float s = b_hh[j] + b_xh[j];
    for (int k = 0; k < 512; k += 4) {
        const float4 w = *(const float4*)&W_xh[(size_t)j * 512 + k];
        const float4 b = *(const float4*)&b_hy[k];
        s += w.x * b.x + w.y * b.y + w.z * b.z + w.w * b.w;
    }
    out[j] = s;
}

// hs_final: h2 rows at n = b*S + (S-1), f16 -> fp32
__global__ void hs_kernel(const f16* __restrict__ h2, float* __restrict__ out)
{
    const int t = blockIdx.x * 256 + threadIdx.x;   // 0..4095
    const int b = t >> 9, j = t & 511;
    out[t] = (float)h2[((size_t)b * SLEN + (SLEN - 1)) * KDIM + j];
}

extern "C" void kernel_launch(void* const* d_in, const int* in_sizes, int n_in,
                              void* d_out, int out_size, void* d_ws, size_t ws_size,
                              hipStream_t stream)
{
    (void)in_sizes; (void)n_in; (void)out_size; (void)ws_size;

    const float* xs     = (const float*)d_in[0];
    const float* W_xh0  = (const float*)d_in[1];
    const float* b_xh0  = (const float*)d_in[2];
    /* d_in[3] = W_hh0 unused (hs==0; only its bias matters) */
    const float* b_hh0  = (const float*)d_in[4];
    const float* W_hy0  = (const float*)d_in[5];
    const float* b_hy0  = (const float*)d_in[6];
    const float* W_xh_h = (const float*)d_in[7];
    const float* b_xh_h = (const float*)d_in[8];
    const float* W_hh_h = (const float*)d_in[9];
    const float* b_hh_h = (const float*)d_in[10];
    const float* W_hy_h = (const float*)d_in[11];
    const float* b_hy_h = (const float*)d_in[12];

    f16* bufA   = (f16*)d_ws;                    // 32 MB
    f16* bufB   = bufA + (size_t)NTOK * KDIM;    // 32 MB
    f16* w_xh0  = bufB + (size_t)NTOK * KDIM;    // f16 weights area (~4 MB)
    f16* w_xhh  = w_xh0 + WSZ;                   // 2 layers
    f16* w_hy1  = w_xhh + 2 * WSZ;
    f16* wt0    = w_hy1 + WSZ;                   // W_hy0^T
    f16* wt1    = wt0 + WSZ;                     // W_hy_h[0]^T
    f16* weff0  = wt1 + WSZ;
    f16* weff1  = weff0 + WSZ;
    float* beff0 = (float*)(weff1 + WSZ);
    float* beff1 = beff0 + 512;

    dim3 block(256);

    // ---- prep: conversions / transposes / weight folds / bias folds ----
    cvt_kernel<<<NTOK * KDIM / 2048, block, 0, stream>>>(xs, bufA);          // X -> f16
    cvt_kernel<<<WSZ / 2048, block, 0, stream>>>(W_xh0, w_xh0);
    cvt_kernel<<<2 * WSZ / 2048, block, 0, stream>>>(W_xh_h, w_xhh);
    cvt_kernel<<<WSZ / 2048, block, 0, stream>>>(W_hy_h + WSZ, w_hy1);
    tcvt_kernel<<<64, block, 0, stream>>>(W_hy0, wt0);
    tcvt_kernel<<<64, block, 0, stream>>>(W_hy_h, wt1);
    // W_eff[li] = W_hh_h[li] + W_xh_h[li] @ W_hy_prev   (f16 out, fp32 C-add)
    gemm16<false,false,true,false,0,true><<<16, block, 0, stream>>>(
        w_xhh,       wt0, nullptr, nullptr, W_hh_h,       weff0);
    gemm16<false,false,true,false,0,true><<<16, block, 0, stream>>>(
        w_xhh + WSZ, wt1, nullptr, nullptr, W_hh_h + WSZ, weff1);
    beff_kernel<<<2, block, 0, stream>>>(W_xh_h,       b_hy0,        b_hh_h,        b_xh_h,        beff0);
    beff_kernel<<<2, block, 0, stream>>>(W_xh_h + WSZ, b_hy_h,       b_hh_h + KDIM, b_xh_h + KDIM, beff1);

    // ---- main chain: 4 big GEMMs ----
    dim3 grid(1024);
    // h0 = tanh(X16 @ W_xh0^T + b_xh0 + b_hh0) -> bufB
    gemm16<true,true,false,true,0,false><<<grid, block, 0, stream>>>(
        bufA, w_xh0, b_xh0, b_hh0, nullptr, bufB);
    // h1 = tanh(h0 @ W_eff0^T + b_eff0) -> bufA
    gemm16<true,false,false,true,0,false><<<grid, block, 0, stream>>>(
        bufB, weff0, beff0, nullptr, nullptr, bufA);
    // h2 = tanh(h1 @ W_eff1^T + b_eff1) -> bufB
    gemm16<true,false,false,true,0,false><<<grid, block, 0, stream>>>(
        bufA, weff1, beff1, nullptr, nullptr, bufB);
    // y2 = h2 @ W_hy_h[1]^T + b_hy_h[1] -> d_out (fp32, [S,B,H])
    gemm16<true,false,false,false,1,false><<<grid, block, 0, stream>>>(
        bufB, w_hy1, b_hy_h + KDIM, nullptr, nullptr, d_out);
    // hs_final = h2[:, S-1, :] -> tail of d_out
    hs_kernel<<<16, block, 0, stream>>>(
        bufB, (float*)d_out + (size_t)SLEN * BATCH * KDIM);
}

// Round 6
// 275.347 us; speedup vs baseline: 1.7351x; 1.2046x over previous
//
#include <hip/hip_runtime.h>
#include <hip/hip_fp16.h>

typedef _Float16 f16;
typedef f16 f16x4 __attribute__((ext_vector_type(4)));
typedef f16 f16x8 __attribute__((ext_vector_type(8)));
typedef float f32x4 __attribute__((ext_vector_type(4)));

#define NTOK 32768   // B*S
#define KDIM 512
#define SLEN 4096
#define BATCH 8
#define WSZ  262144  // 512*512

#define GLOAD_LDS16(g, l) __builtin_amdgcn_global_load_lds(                 \
    (const __attribute__((address_space(1))) void*)(g),                     \
    (__attribute__((address_space(3))) void*)(l), 16, 0, 0)

__device__ __forceinline__ float fast_tanh(float x) {
    float ax = fabsf(x);
    float t = __expf(-2.0f * ax);
    float r = (1.0f - t) / (1.0f + t);
    return copysignf(r, x);
}

// =====================  fused 4-phase chain  =====================
// Each block owns 128 tokens. LDS holds h (or X) as [token 128][feature 512] f16,
// XOR-swizzled in 16B chunks: element (m, f) lives at m*512 + ((f>>3 ^ (m&7))<<3) + (f&7).
// Phases compute D^T[feature][token] = mfma(W_rowfrag, h_frag): lane holds
// col = token (fr), rows = 4 consecutive features (q*4+r)  -> b64 LDS write-back.
__global__ __launch_bounds__(512, 2)
void chain_kernel(const float* __restrict__ xs,
                  const f16*  __restrict__ Wp,    // [4][512*512] f16 row-major [j][k]
                  const float* __restrict__ bias, // [4][512] fp32
                  float* __restrict__ out)        // y2 [S,B,512] then hs [8*512]
{
    __shared__ f16 hbuf[128][512];   // 128 KB

    const int tid  = threadIdx.x;
    const int bid  = blockIdx.x;
    const int n0   = bid * 128;
    const int lane = tid & 63;
    const int wave = tid >> 6;       // 0..7: wave owns features [wave*64, +64)
    const int fr   = lane & 15;      // token within 16-tile (D^T col)
    const int q    = lane >> 4;      // 0..3
    const int j0w  = wave * 64;

    // ---- stage X tile: fp32 -> f16 into hbuf (swizzled) ----
    {
        const int tk = tid >> 2;                 // 0..127
        const int cq = tid & 3;                  // 0..3
        const float* __restrict__ src = &xs[(size_t)(n0 + tk) * KDIM];
        #pragma unroll
        for (int kt = 0; kt < 16; ++kt) {
            const int k = kt * 32 + cq * 8;
            const float4 v0 = *(const float4*)&src[k];
            const float4 v1 = *(const float4*)&src[k + 4];
            f16x8 h;
            h[0]=(f16)v0.x; h[1]=(f16)v0.y; h[2]=(f16)v0.z; h[3]=(f16)v0.w;
            h[4]=(f16)v1.x; h[5]=(f16)v1.y; h[6]=(f16)v1.z; h[7]=(f16)v1.w;
            const int c = (k >> 3) ^ (tk & 7);
            *(f16x8*)&hbuf[tk][c << 3] = h;
        }
    }

    f32x4 acc[4][8];   // [jt][mt] : 128 AGPRs

    // ---- phases 0..2: h = tanh(h_prev @ W^T + b), in-place in LDS ----
    for (int ph = 0; ph < 3; ++ph) {
        const f16*   __restrict__ wp = Wp + (size_t)ph * WSZ;
        const float* __restrict__ bp = bias + ph * KDIM;
        f32x4 bv[4];
        #pragma unroll
        for (int jt = 0; jt < 4; ++jt)
            bv[jt] = *(const f32x4*)&bp[j0w + jt * 16 + q * 4];
        #pragma unroll
        for (int jt = 0; jt < 4; ++jt)
            #pragma unroll
            for (int mt = 0; mt < 8; ++mt)
                acc[jt][mt] = bv[jt];

        __syncthreads();   // h (or X) writes visible before reads

        for (int kt = 0; kt < 16; ++kt) {
            f16x8 wf[4], hf[8];
            #pragma unroll
            for (int jt = 0; jt < 4; ++jt)
                wf[jt] = *(const f16x8*)&wp[(size_t)(j0w + jt*16 + fr) * KDIM + kt*32 + q*8];
            #pragma unroll
            for (int mt = 0; mt < 8; ++mt) {
                const int m = mt * 16 + fr;
                const int c = (kt * 4 + q) ^ (m & 7);
                hf[mt] = *(const f16x8*)&hbuf[m][c << 3];
            }
            #pragma unroll
            for (int jt = 0; jt < 4; ++jt)
                #pragma unroll
                for (int mt = 0; mt < 8; ++mt)
                    acc[jt][mt] = __builtin_amdgcn_mfma_f32_16x16x32_f16(
                        wf[jt], hf[mt], acc[jt][mt], 0, 0, 0);
        }

        __syncthreads();   // all reads done before overwrite

        #pragma unroll
        for (int jt = 0; jt < 4; ++jt) {
            const int j0f  = j0w + jt * 16 + q * 4;   // 4 consecutive features
            const int c    = j0f >> 3;
            const int half = j0f & 7;                 // 0 or 4
            #pragma unroll
            for (int mt = 0; mt < 8; ++mt) {
                const int m = mt * 16 + fr;
                f16x4 hv;
                hv[0] = (f16)fast_tanh(acc[jt][mt][0]);
                hv[1] = (f16)fast_tanh(acc[jt][mt][1]);
                hv[2] = (f16)fast_tanh(acc[jt][mt][2]);
                hv[3] = (f16)fast_tanh(acc[jt][mt][3]);
                *(f16x4*)&hbuf[m][((c ^ (m & 7)) << 3) + half] = hv;
            }
        }
    }

    // ---- phase 3: y2 = h2 @ W_hy1^T + b -> global (D^T layout matches [s,b,j]) ----
    {
        const f16*   __restrict__ wp = Wp + (size_t)3 * WSZ;
        const float* __restrict__ bp = bias + 3 * KDIM;
        f32x4 bv[4];
        #pragma unroll
        for (int jt = 0; jt < 4; ++jt)
            bv[jt] = *(const f32x4*)&bp[j0w + jt * 16 + q * 4];
        #pragma unroll
        for (int jt = 0; jt < 4; ++jt)
            #pragma unroll
            for (int mt = 0; mt < 8; ++mt)
                acc[jt][mt] = bv[jt];

        __syncthreads();   // h2 writes visible

        // hs_final: blocks holding token s==4095 (bid = 32b+31, local token 127)
        if ((bid & 31) == 31) {
            const int f = tid;                      // feature 0..511
            const int c = (f >> 3) ^ 7;             // m=127 -> m&7 = 7
            out[(size_t)SLEN * BATCH * KDIM + (size_t)(bid >> 5) * KDIM + f] =
                (float)hbuf[127][(c << 3) + (f & 7)];
        }

        for (int kt = 0; kt < 16; ++kt) {
            f16x8 wf[4], hf[8];
            #pragma unroll
            for (int jt = 0; jt < 4; ++jt)
                wf[jt] = *(const f16x8*)&wp[(size_t)(j0w + jt*16 + fr) * KDIM + kt*32 + q*8];
            #pragma unroll
            for (int mt = 0; mt < 8; ++mt) {
                const int m = mt * 16 + fr;
                const int c = (kt * 4 + q) ^ (m & 7);
                hf[mt] = *(const f16x8*)&hbuf[m][c << 3];
            }
            #pragma unroll
            for (int jt = 0; jt < 4; ++jt)
                #pragma unroll
                for (int mt = 0; mt < 8; ++mt)
                    acc[jt][mt] = __builtin_amdgcn_mfma_f32_16x16x32_f16(
                        wf[jt], hf[mt], acc[jt][mt], 0, 0, 0);
        }

        #pragma unroll
        for (int jt = 0; jt < 4; ++jt) {
            const int j = j0w + jt * 16 + q * 4;
            #pragma unroll
            for (int mt = 0; mt < 8; ++mt) {
                const int n  = n0 + mt * 16 + fr;
                const int s  = n & (SLEN - 1);
                const int bb = n >> 12;
                *(f32x4*)&out[(size_t)(s * BATCH + bb) * KDIM + j] = acc[jt][mt];
            }
        }
    }
}

// =====================  fold GEMM (proven round-5 path)  =====================
// C[n,j] = sum_k A[n,k]*W[j,k] + Cadd[n,j]  -> f16 out.  512x512, 16 blocks.
__global__ __launch_bounds__(256)
void gemm16_fold(const f16* __restrict__ A, const f16* __restrict__ W,
                 const float* __restrict__ Cadd, f16* __restrict__ Cp)
{
    __shared__ f16 A_s[128][64];
    __shared__ f16 B_s[128][64];

    const int tid = threadIdx.x;
    const int bid = blockIdx.x;
    const int n0 = (bid >> 2) * 128;
    const int j0 = (bid & 3) * 128;

    const int lane = tid & 63, wave = tid >> 6;
    const int wm = wave >> 1, wn = wave & 1;
    const int fr = lane & 15, q = lane >> 4, sw = fr & 7;
    const int ar8 = lane >> 3;
    const int ach = (lane & 7) ^ ar8;

    f32x4 acc[4][4] = {};

    for (int kt = 0; kt < 8; ++kt) {
        const int k0 = kt * 64;
        #pragma unroll
        for (int p = 0; p < 4; ++p) {
            const int r8 = wave * 32 + p * 8;
            GLOAD_LDS16(&A[(size_t)(n0 + r8 + ar8) * KDIM + k0 + (ach << 3)], &A_s[r8][0]);
            GLOAD_LDS16(&W[(size_t)(j0 + r8 + ar8) * KDIM + k0 + (ach << 3)], &B_s[r8][0]);
        }
        __syncthreads();
        #pragma unroll
        for (int kc = 0; kc < 8; kc += 4) {
            f16x8 a[4], b[4];
            #pragma unroll
            for (int t = 0; t < 4; ++t)
                a[t] = *(const f16x8*)&A_s[wm * 64 + t * 16 + fr][((kc + q) ^ sw) << 3];
            #pragma unroll
            for (int t = 0; t < 4; ++t)
                b[t] = *(const f16x8*)&B_s[wn * 64 + t * 16 + fr][((kc + q) ^ sw) << 3];
            #pragma unroll
            for (int im = 0; im < 4; ++im)
                #pragma unroll
                for (int jn = 0; jn < 4; ++jn)
                    acc[im][jn] = __builtin_amdgcn_mfma_f32_16x16x32_f16(
                        a[im], b[jn], acc[im][jn], 0, 0, 0);
        }
        __syncthreads();
    }

    const int r0 = q * 4, c = fr;
    #pragma unroll
    for (int jn = 0; jn < 4; ++jn) {
        const int j = j0 + wn * 64 + jn * 16 + c;
        #pragma unroll
        for (int im = 0; im < 4; ++im)
            #pragma unroll
            for (int r = 0; r < 4; ++r) {
                const int n = n0 + wm * 64 + im * 16 + r0 + r;
                Cp[(size_t)n * KDIM + j] =
                    (f16)(acc[im][jn][r] + Cadd[(size_t)n * KDIM + j]);
            }
    }
}

// =====================  prep: all cvt/tcvt in one launch  =====================
__device__ __forceinline__ void cvt2048(const float* __restrict__ src, f16* __restrict__ dst, int t)
{
    const float4 v0 = *(const float4*)&src[(size_t)t * 8];
    const float4 v1 = *(const float4*)&src[(size_t)t * 8 + 4];
    f16x8 h;
    h[0]=(f16)v0.x; h[1]=(f16)v0.y; h[2]=(f16)v0.z; h[3]=(f16)v0.w;
    h[4]=(f16)v1.x; h[5]=(f16)v1.y; h[6]=(f16)v1.z; h[7]=(f16)v1.w;
    *(f16x8*)&dst[(size_t)t * 8] = h;
}

__device__ __forceinline__ void tcvt64(const float* __restrict__ in, f16* __restrict__ out, int b, int tid)
{
    __shared__ float t[64][65];
    const int c0 = (b & 7) * 64, r0 = (b >> 3) * 64;
    const int tr = tid >> 4;
    const int tc = (tid & 15) * 4;
    #pragma unroll
    for (int i = 0; i < 4; ++i) {
        const float4 v = *(const float4*)&in[(size_t)(r0 + tr + 16 * i) * 512 + c0 + tc];
        t[tr + 16 * i][tc + 0] = v.x; t[tr + 16 * i][tc + 1] = v.y;
        t[tr + 16 * i][tc + 2] = v.z; t[tr + 16 * i][tc + 3] = v.w;
    }
    __syncthreads();
    #pragma unroll
    for (int i = 0; i < 4; ++i) {
        const int cl = tr + 16 * i;
        f16x4 h;
        h[0] = (f16)t[tc + 0][cl]; h[1] = (f16)t[tc + 1][cl];
        h[2] = (f16)t[tc + 2][cl]; h[3] = (f16)t[tc + 3][cl];
        *(f16x4*)&out[(size_t)(c0 + cl) * 512 + r0 + tc] = h;
    }
}

__global__ __launch_bounds__(256)
void prep_cvt(const float* __restrict__ W_xh0, const float* __restrict__ W_xh_h,
              const float* __restrict__ W_hy_h, const float* __restrict__ W_hy0,
              f16* __restrict__ Wp, f16* __restrict__ w_xhh, f16* __restrict__ wt)
{
    const int b = blockIdx.x, tid = threadIdx.x;
    if (b < 128)      cvt2048(W_xh0,            Wp,             b * 256 + tid);
    else if (b < 384) cvt2048(W_xh_h,           w_xhh,          (b - 128) * 256 + tid);
    else if (b < 512) cvt2048(W_hy_h + WSZ,     Wp + 3 * WSZ,   (b - 384) * 256 + tid);
    else if (b < 576) tcvt64(W_hy0,  wt,        b - 512, tid);
    else              tcvt64(W_hy_h, wt + WSZ,  b - 576, tid);
}

// =====================  bias prep: bias[4][512]  =====================
__global__ __launch_bounds__(256)
void bias_prep(const float* __restrict__ b_xh0, const float* __restrict__ b_hh0,
               const float* __restrict__ W_xh_h, const float* __restrict__ b_xh_h,
               const float* __restrict__ b_hh_h, const float* __restrict__ b_hy0,
               const float* __restrict__ b_hy_h, float* __restrict__ bias)
{
    const int b = blockIdx.x;
    const int row = b >> 1;
    const int j = (b & 1) * 256 + threadIdx.x;
    float v;
    if (row == 0)      v = b_xh0[j] + b_hh0[j];
    else if (row == 3) v = b_hy_h[KDIM + j];
    else {
        const int li = row - 1;
        const float* __restrict__ W  = W_xh_h + (size_t)li * WSZ;
        const float* __restrict__ bh = li ? b_hy_h : b_hy0;   // b_hy of previous cell
        v = b_hh_h[li * KDIM + j] + b_xh_h[li * KDIM + j];
        for (int k = 0; k < 512; k += 4) {
            const float4 w  = *(const float4*)&W[(size_t)j * 512 + k];
            const float4 bb = *(const float4*)&bh[k];
            v += w.x * bb.x + w.y * bb.y + w.z * bb.z + w.w * bb.w;
        }
    }
    bias[row * KDIM + j] = v;
}

extern "C" void kernel_launch(void* const* d_in, const int* in_sizes, int n_in,
                              void* d_out, int out_size, void* d_ws, size_t ws_size,
                              hipStream_t stream)
{
    (void)in_sizes; (void)n_in; (void)out_size; (void)ws_size;

    const float* xs     = (const float*)d_in[0];
    const float* W_xh0  = (const float*)d_in[1];
    const float* b_xh0  = (const float*)d_in[2];
    /* d_in[3] = W_hh0 unused (hs==0; only its bias matters) */
    const float* b_hh0  = (const float*)d_in[4];
    const float* W_hy0  = (const float*)d_in[5];
    const float* b_hy0  = (const float*)d_in[6];
    const float* W_xh_h = (const float*)d_in[7];
    const float* b_xh_h = (const float*)d_in[8];
    const float* W_hh_h = (const float*)d_in[9];
    const float* b_hh_h = (const float*)d_in[10];
    const float* W_hy_h = (const float*)d_in[11];
    const float* b_hy_h = (const float*)d_in[12];

    f16*   Wp    = (f16*)d_ws;                 // [4][WSZ] phase weights
    f16*   w_xhh = Wp + 4 * WSZ;               // fold inputs
    f16*   wt    = w_xhh + 2 * WSZ;            // W_hy0^T, W_hy_h[0]^T
    float* bias  = (float*)(wt + 2 * WSZ);     // [4][512]

    dim3 block(256);

    // prep: all conversions/transposes in one launch; biases in another
    prep_cvt<<<640, block, 0, stream>>>(W_xh0, W_xh_h, W_hy_h, W_hy0, Wp, w_xhh, wt);
    bias_prep<<<8, block, 0, stream>>>(b_xh0, b_hh0, W_xh_h, b_xh_h, b_hh_h,
                                       b_hy0, b_hy_h, bias);
    // W_eff[li] = W_hh_h[li] + W_xh_h[li] @ W_hy_prev  -> Wp[1+li]
    gemm16_fold<<<16, block, 0, stream>>>(w_xhh,       wt,       W_hh_h,       Wp + WSZ);
    gemm16_fold<<<16, block, 0, stream>>>(w_xhh + WSZ, wt + WSZ, W_hh_h + WSZ, Wp + 2 * WSZ);

    // fused chain: 256 blocks x 512 threads, 1 block/CU
    chain_kernel<<<256, dim3(512), 0, stream>>>(xs, Wp, bias, (float*)d_out);
}